// Round 6
// baseline (120.278 us; speedup 1.0000x reference)
//
#include <hip/hip_runtime.h>

// Encode 11x11 hex boards -> (B, 27, 12, 12) one-hot float32 tensor.
// Store-BW-bound: 509.6 MB out. Two-kernel split to get a fill-kernel-shaped
// write stream:
//   k1: boards -> per-cell 9-bit masks in d_ws (9.4 MB)
//   k2: grid-stride slab streamer -- at any instant the whole device writes
//       ONE contiguous 8 MB slab that slides through the output (narrow
//       instantaneous address window, like __amd_rocclr_fillBufferAligned).

#define G    8                    // boards per block in k1
#define K2_BLOCKS 2048
#define K2_THREADS 256
#define K2_STRIDE (K2_BLOCKS * K2_THREADS)   // 524288 threads = 8 MB f4 slab

typedef float f4 __attribute__((ext_vector_type(4)));

__global__ __launch_bounds__(256) void mask_kernel(
    const float* __restrict__ boards, unsigned long long* __restrict__ ws)
{
    __shared__ float sP[G][169];                           // padded 13x13 boards
    __shared__ __align__(16) unsigned short sMask[G][144]; // per-cell 9-bit masks

    const int tid = threadIdx.x;
    const size_t b0 = (size_t)blockIdx.x * G;

    // Phase 1: padded P (13x13) for G boards; all loads independent.
    #pragma unroll
    for (int it = 0; it < 6; ++it) {
        int idx = tid + it * 256;
        if (idx < G * 169) {
            int g = idx / 169;
            int pos = idx - g * 169;
            int pr = pos / 13, pc = pos % 13;
            bool ir = (pr >= 1) & (pr <= 11);
            bool jr = (pc >= 1) & (pc <= 11);
            float v;
            if (ir & jr)  v = boards[(b0 + g) * 121 + (pr - 1) * 11 + (pc - 1)];
            else if (jr)  v = 1.0f;    // top/bottom edge rows
            else if (ir)  v = -1.0f;   // left/right edge cols
            else          v = 0.0f;    // corners
            sP[g][pos] = v;
        }
    }
    __syncthreads();

    // Phase 2: per-cell masks (3 one-hot 3-bit fields; corner cells -> 0b111).
    #pragma unroll
    for (int it = 0; it < 5; ++it) {
        int idx = tid + it * 256;
        if (idx < G * 144) {
            int g = idx / 144;
            int cell = idx - g * 144;
            int r = cell / 12, c = cell - 12 * r;
            const float* P = sP[g];
            int i0 = (int)P[r * 13 + c] + 1;        // a0 = P[r][c]
            int i1 = (int)P[r * 13 + c + 1] + 1;    // a1 = P[r][c+1]
            int i2 = (int)P[(r + 1) * 13 + c] + 1;  // a2 = P[r+1][c]
            unsigned m0 = (cell == 0)   ? 7u : (1u << i0);   // eq0 @ (0,0)
            unsigned m1 = (cell == 11)  ? 7u : (1u << i1);   // eq1 @ (0,11)
            unsigned m2 = (cell == 132) ? 7u : (1u << i2);   // eq2 @ (11,0)
            sMask[g][cell] = (unsigned short)(m0 | (m1 << 3) | (m2 << 6));
        }
    }
    __syncthreads();

    // Copy masks out: G*144 u16 = 2304 B = 144 x 16 B, coalesced.
    if (tid < G * 18) {
        ((ulonglong2*)(ws + (size_t)blockIdx.x * (G * 36)))[tid] =
            ((const ulonglong2*)sMask)[tid];
    }
}

__global__ __launch_bounds__(K2_THREADS) void stream_kernel(
    const unsigned long long* __restrict__ masks, float* __restrict__ out)
{
    __shared__ unsigned sNeed[32];   // pattern -> need bits
    const int tid = threadIdx.x;
    if (tid < 27) {
        int v0 = tid / 9, v1 = (tid / 3) % 3, v2 = tid % 3;
        sNeed[tid] = (1u << v0) | (1u << (3 + v1)) | (1u << (6 + v2));
    }
    __syncthreads();

    const unsigned TOTAL = 32768u * 972u;    // 31,850,496 float4
    f4* outv = (f4*)out;

    #pragma unroll 2
    for (unsigned idx = blockIdx.x * K2_THREADS + tid; idx < TOTAL;
         idx += K2_STRIDE) {
        unsigned b = idx / 972u;             // magic-mul
        unsigned rem = idx - b * 972u;
        unsigned p = rem / 36u;              // pattern 0..26
        unsigned cell4 = rem - p * 36u;      // float4 group within 144 cells
        unsigned need = sNeed[p];
        unsigned long long m4 = masks[b * 36u + cell4];  // L2-warm 8B load
        f4 o;
        o.x = (((unsigned)(m4)       & need) == need) ? 1.0f : 0.0f;
        o.y = (((unsigned)(m4 >> 16) & need) == need) ? 1.0f : 0.0f;
        o.z = (((unsigned)(m4 >> 32) & need) == need) ? 1.0f : 0.0f;
        o.w = (((unsigned)(m4 >> 48) & need) == need) ? 1.0f : 0.0f;
        outv[idx] = o;
    }
}

extern "C" void kernel_launch(void* const* d_in, const int* in_sizes, int n_in,
                              void* d_out, int out_size, void* d_ws, size_t ws_size,
                              hipStream_t stream) {
    const float* boards = (const float*)d_in[0];
    float* out = (float*)d_out;
    unsigned long long* ws = (unsigned long long*)d_ws;
    mask_kernel<<<32768 / G, 256, 0, stream>>>(boards, ws);
    stream_kernel<<<K2_BLOCKS, K2_THREADS, 0, stream>>>(ws, out);
}

// Round 7
// 104.592 us; speedup vs baseline: 1.1500x; 1.1500x over previous
//
#include <hip/hip_runtime.h>

// Encode 11x11 hex boards -> (B, 27, 12, 12) one-hot float32 tensor.
// Store-BW-bound: 509.6 MB out. R0 structure (1 board/block, 32768 blocks)
// with ONE change: the output is fully materialized in LDS first, so the
// store loop is a pure linear LDS->global copy (ds_read_b128 +
// global_store_dwordx4, no VALU, no dependent compute) -- the same loop
// body shape as the 6.9 TB/s fill kernel.

typedef float f4 __attribute__((ext_vector_type(4)));

__global__ __launch_bounds__(256) void hex_encode_kernel(
    const float* __restrict__ boards, float* __restrict__ out)
{
    __shared__ float sP[169];                          // padded 13x13 board
    __shared__ __align__(8) unsigned short sM[144];    // per-cell 9-bit masks
    __shared__ unsigned sNeed[32];                     // pattern -> need bits
    __shared__ __align__(16) float sOut[3888];         // full board output

    const int tid = threadIdx.x;
    const size_t b = blockIdx.x;
    const float* board = boards + b * 121;

    if (tid < 27) {
        int v0 = tid / 9, v1 = (tid / 3) % 3, v2 = tid % 3;
        sNeed[tid] = (1u << v0) | (1u << (3 + v1)) | (1u << (6 + v2));
    }

    // Phase 1: padded P (13x13).
    if (tid < 169) {
        int pr = tid / 13, pc = tid % 13;
        bool ir = (pr >= 1) & (pr <= 11);
        bool jr = (pc >= 1) & (pc <= 11);
        float v;
        if (ir & jr)  v = board[(pr - 1) * 11 + (pc - 1)];
        else if (jr)  v = 1.0f;    // top/bottom edge rows
        else if (ir)  v = -1.0f;   // left/right edge cols
        else          v = 0.0f;    // corners
        sP[tid] = v;
    }
    __syncthreads();

    // Phase 2: per-cell 9-bit masks (3 one-hot fields; corner cells -> 0b111).
    if (tid < 144) {
        int r = tid / 12, c = tid - 12 * r;
        int i0 = (int)sP[r * 13 + c] + 1;        // a0 = P[r][c]
        int i1 = (int)sP[r * 13 + c + 1] + 1;    // a1 = P[r][c+1]
        int i2 = (int)sP[(r + 1) * 13 + c] + 1;  // a2 = P[r+1][c]
        unsigned m0 = (tid == 0)   ? 7u : (1u << i0);   // eq0 @ (0,0)
        unsigned m1 = (tid == 11)  ? 7u : (1u << i1);   // eq1 @ (0,11)
        unsigned m2 = (tid == 132) ? 7u : (1u << i2);   // eq2 @ (11,0)
        sM[tid] = (unsigned short)(m0 | (m1 << 3) | (m2 << 6));
    }
    __syncthreads();

    // Phase 3: materialize all 972 f4 of this board's output into LDS.
    {
        f4* so = (f4*)sOut;
        const unsigned long long* m64 = (const unsigned long long*)sM;
        #pragma unroll
        for (int it = 0; it < 4; ++it) {
            int idx = tid + it * 256;
            if (idx < 972) {
                unsigned p = (unsigned)idx / 36u;       // pattern 0..26
                unsigned cell4 = (unsigned)idx - p * 36u;
                unsigned need = sNeed[p];
                unsigned long long m4 = m64[cell4];
                f4 o;
                o.x = (((unsigned)(m4)       & need) == need) ? 1.0f : 0.0f;
                o.y = (((unsigned)(m4 >> 16) & need) == need) ? 1.0f : 0.0f;
                o.z = (((unsigned)(m4 >> 32) & need) == need) ? 1.0f : 0.0f;
                o.w = (((unsigned)(m4 >> 48) & need) == need) ? 1.0f : 0.0f;
                so[idx] = o;
            }
        }
    }
    __syncthreads();

    // Phase 4: fill-shaped store loop -- pure linear LDS->global copy.
    {
        const f4* so = (const f4*)sOut;
        f4* outv = (f4*)out + b * 972;
        #pragma unroll
        for (int it = 0; it < 4; ++it) {
            int idx = tid + it * 256;
            if (idx < 972)
                outv[idx] = so[idx];
        }
    }
}

extern "C" void kernel_launch(void* const* d_in, const int* in_sizes, int n_in,
                              void* d_out, int out_size, void* d_ws, size_t ws_size,
                              hipStream_t stream) {
    const float* boards = (const float*)d_in[0];
    float* out = (float*)d_out;
    hex_encode_kernel<<<32768, 256, 0, stream>>>(boards, out);
}

// Round 8
// 100.547 us; speedup vs baseline: 1.1962x; 1.0402x over previous
//
#include <hip/hip_runtime.h>

// Encode 11x11 hex boards -> (B, 27, 12, 12) one-hot pattern tensor.
// Memory-bound: 509.6 MB output stream. One block per board.
//
// CHAMPION (R0 structure). Seven structural variants tested and all lost:
//   nt-stores / multi-board blocks (106.5), kernel split (118.8),
//   persistent waves (111.8), fill-shaped sweep (106.6), grid-stride
//   (120.3), LDS-materialized pure-copy store loop (104.6).
// In-loop compute is free under store drain; added structure only adds cost.
// ~100 us = 525.6 MB @ ~6.3 TB/s (83 us) + ~10 us launch + ramp/mixing.

__global__ __launch_bounds__(256) void hex_encode_kernel(
    const float* __restrict__ boards, float* __restrict__ out)
{
    __shared__ float sP[169];                          // 13x13 padded board
    __shared__ __align__(16) unsigned short sMask[144]; // per-cell 9-bit match mask

    const int tid = threadIdx.x;
    const int b = blockIdx.x;
    const float* board = boards + (size_t)b * 121;

    // Build padded P (13x13): interior = board, top/bottom edges = +1,
    // left/right edges = -1, corners = 0.
    if (tid < 169) {
        int pr = tid / 13, pc = tid % 13;
        bool ir = (pr >= 1) & (pr <= 11);
        bool jr = (pc >= 1) & (pc <= 11);
        float v;
        if (ir & jr)  v = board[(pr - 1) * 11 + (pc - 1)];
        else if (jr)  v = 1.0f;    // pr == 0 or 12
        else if (ir)  v = -1.0f;   // pc == 0 or 12
        else          v = 0.0f;    // corners
        sP[tid] = v;
    }
    __syncthreads();

    // Per-cell mask: 3 fields of 3 bits, one-hot on (value+1), or 0b111 at
    // the three corner-override cells (exactly where a corner of P is read).
    if (tid < 144) {
        int r = tid / 12, c = tid % 12;
        int i0 = (int)sP[r * 13 + c] + 1;        // a0 = P[r][c]
        int i1 = (int)sP[r * 13 + c + 1] + 1;    // a1 = P[r][c+1]
        int i2 = (int)sP[(r + 1) * 13 + c] + 1;  // a2 = P[r+1][c]
        unsigned m0 = (tid == 0)   ? 7u : (1u << i0);   // eq0 override at (0,0)
        unsigned m1 = (tid == 11)  ? 7u : (1u << i1);   // eq1 override at (0,11)
        unsigned m2 = (tid == 132) ? 7u : (1u << i2);   // eq2 override at (11,0)
        sMask[tid] = (unsigned short)(m0 | (m1 << 3) | (m2 << 6));
    }
    __syncthreads();

    // Write 3888 floats = 972 float4 per board, coalesced.
    float* outb = out + (size_t)b * 3888;
    const unsigned long long* mask64 = (const unsigned long long*)sMask;
    #pragma unroll
    for (int it = 0; it < 4; ++it) {
        int idx = tid + it * 256;          // float4 index in [0, 972)
        if (idx < 972) {
            int p = idx / 36;              // pattern 0..26 (144 elems = 36 float4 per p)
            int cell4 = idx - p * 36;      // group of 4 cells within the 144
            int v0 = p / 9, v1 = (p / 3) % 3, v2 = p % 3;
            unsigned need = (1u << v0) | (1u << (3 + v1)) | (1u << (6 + v2));
            unsigned long long m4 = mask64[cell4];  // 4 cells' masks, one b64 read
            float4 o;
            o.x = (((unsigned)(m4)       & need) == need) ? 1.0f : 0.0f;
            o.y = (((unsigned)(m4 >> 16) & need) == need) ? 1.0f : 0.0f;
            o.z = (((unsigned)(m4 >> 32) & need) == need) ? 1.0f : 0.0f;
            o.w = (((unsigned)(m4 >> 48) & need) == need) ? 1.0f : 0.0f;
            *(float4*)(outb + idx * 4) = o;
        }
    }
}

extern "C" void kernel_launch(void* const* d_in, const int* in_sizes, int n_in,
                              void* d_out, int out_size, void* d_ws, size_t ws_size,
                              hipStream_t stream) {
    const float* boards = (const float*)d_in[0];
    float* out = (float*)d_out;
    hex_encode_kernel<<<32768, 256, 0, stream>>>(boards, out);
}